// Round 7
// baseline (1026.301 us; speedup 1.0000x reference)
//
#include <hip/hip_runtime.h>

typedef float f32x4 __attribute__((ext_vector_type(4)));
typedef short bf16x8 __attribute__((ext_vector_type(8)));

#define T_LEN 96
#define DM    256
#define NSAMP 64      // ODE rows per block
#define MT 2          // d-tiles per wave (wave owns 32 d)
#define NT 2          // sample-tiles per wave (wave group owns 32 samples)

__device__ __forceinline__ uint bf16h(float x){            // f32 -> bf16 bits, RNE
    uint u = __float_as_uint(x);
    return (u + 0x7fffu + ((u>>16)&1u)) >> 16;
}
__device__ __forceinline__ float bf16f(uint h){ return __uint_as_float(h<<16); }
__device__ __forceinline__ float softplus_f(float x){
    return fmaxf(x,0.f) + log1pf(__expf(-fabsf(x)));
}

// Split W into bf16 hi/lo and pack into MFMA A-fragment order:
// frag (dt,ks): lane l holds W[dt*16 + (l&15)][ks*32 + (l>>4)*8 + i], i=0..7
// => packed[((dt*8+ks)*64 + l)*8 + i]; wave64 load = contiguous 1KB.
__global__ void pack_w_kernel(const float* __restrict__ W1, const float* __restrict__ W2,
                              ushort* __restrict__ ws){
    int idx = blockIdx.x*256 + threadIdx.x;          // 0..65535
    const float* W = blockIdx.y ? W2 : W1;
    ushort* hi = ws + (size_t)blockIdx.y*131072;     // [W1hi|W1lo|W2hi|W2lo], 65536 each
    ushort* lo = hi + 65536;
    float w = W[idx];
    uint h = bf16h(w);
    float l = w - bf16f(h);
    uint l16 = bf16h(l);
    int d = idx >> 8, k = idx & 255;
    int off = ((((d>>4)<<3) + (k>>5))<<9) + (((d&15) | (((k>>3)&3)<<4))<<3) + (k&7);
    hi[off] = (ushort)h;
    lo[off] = (ushort)l16;
}

// 16 waves: group g=wv>>3 owns samples [32g,32g+32); wave d-slice wvd=wv&7 owns
// d in [32*wvd, 32*wvd+32).
// __launch_bounds__(1024, 4): 4 waves/EU = 1 block/CU -> VGPR budget 128.
// Without the min-waves arg the compiler targeted 8 waves/EU -> 64 VGPRs and
// spilled ~50 regs/thread (R6: FETCH 587MB + WRITE 624MB of scratch traffic).
// Counted demand ~111 regs -> spill-free at 128.
__global__ __launch_bounds__(1024, 4)
void ode_mfma_kernel(const float* __restrict__ x, const float* __restrict__ t,
                     const float* __restrict__ b1, const float* __restrict__ u1,
                     const float* __restrict__ b2, const float* __restrict__ u2,
                     const ushort* __restrict__ wpk, float* __restrict__ out)
{
    // Y stage: [row 0..63][hi 256 | lo 256] bf16; 16B granules XOR-swizzled by (row&7)
    __shared__ __align__(16) ushort ylds[NSAMP*512];

    const int tid  = threadIdx.x;
    const int wv   = tid >> 6;       // 0..15
    const int wvd  = wv & 7;         // d-slice owner
    const int grp  = wv >> 3;        // sample group
    const int lane = tid & 63;
    const int l15  = lane & 15;
    const int l4   = lane >> 4;
    const int base = blockIdx.x * NSAMP;

    float t0v[NT], rat[NT];
    float y[MT][NT][4], k1[MT][NT][4], k2[MT][NT][4];
    f32x4 acc[MT][NT];

#pragma unroll
    for(int nt=0; nt<NT; nt++){
        int n = base + grp*32 + nt*16 + l15;
        int b = n / (T_LEN*T_LEN);
        int r = n - b*(T_LEN*T_LEN);
        int q = r / T_LEN;
        int j = r - q*T_LEN;
        float ta = t[b*T_LEN + j], tb = t[b*T_LEN + q];
        t0v[nt] = ta; rat[nt] = tb - ta;
        const float* xr = x + (size_t)(b*T_LEN + j)*DM;
#pragma unroll
        for(int mt=0; mt<MT; mt++){
            const int db = 32*wvd + mt*16 + l4*4;
            f32x4 v = *(const f32x4*)(xr + db);
#pragma unroll
            for(int r2=0;r2<4;r2++) y[mt][nt][r2] = v[r2];
        }
    }

    // write 4 consecutive-d values (one D-fragment reg group) as hi/lo bf16 into ylds
    auto put = [&](int mt, int nt, float v0, float v1, float v2, float v3){
        uint h0=bf16h(v0), h1=bf16h(v1), h2=bf16h(v2), h3=bf16h(v3);
        uint hp0 = h0 | (h1<<16), hp1 = h2 | (h3<<16);
        uint lp0 = bf16h(v0 - bf16f(h0)) | (bf16h(v1 - bf16f(h1))<<16);
        uint lp1 = bf16h(v2 - bf16f(h2)) | (bf16h(v3 - bf16f(h3))<<16);
        int row = grp*32 + nt*16 + l15;
        int col = 4*wvd + 2*mt + (l4>>1);       // logical 16B granule (8 k)
        int g   = col ^ (row & 7);              // swizzle low 3 granule bits
        int idx = row*512 + g*8 + (l4&1)*4;
        *(uint2*)&ylds[idx]       = make_uint2(hp0, hp1);   // hi half
        *(uint2*)&ylds[idx + 256] = make_uint2(lp0, lp1);   // lo half
    };

    // acc[mt][nt] = (W-slice) x Y^T over K=256, 3-product bf16 split
    auto matmul = [&](const ushort* Whi){
        const ushort* Wlo = Whi + 65536;
#pragma unroll
        for(int mt=0; mt<MT; mt++)
#pragma unroll
            for(int nt=0; nt<NT; nt++)
                acc[mt][nt] = (f32x4){0.f,0.f,0.f,0.f};
#pragma unroll 2
        for(int ks=0; ks<8; ks++){
            bf16x8 ah[MT], al[MT];
#pragma unroll
            for(int mt=0; mt<MT; mt++){
                const int off = ((((2*wvd+mt)<<3)+ks)<<9) + (lane<<3);
                ah[mt] = *(const bf16x8*)(Whi + off);
                al[mt] = *(const bf16x8*)(Wlo + off);
            }
#pragma unroll
            for(int nt=0; nt<NT; nt++){
                const int row = grp*32 + nt*16 + l15;
                const int gx  = (ks*4 + l4) ^ (row & 7);
                const ushort* bp = &ylds[row*512 + gx*8];
                bf16x8 bh = *(const bf16x8*)bp;
                bf16x8 bl = *(const bf16x8*)(bp + 256);
#pragma unroll
                for(int mt=0; mt<MT; mt++){
                    acc[mt][nt] = __builtin_amdgcn_mfma_f32_16x16x32_bf16(ah[mt], bh, acc[mt][nt], 0,0,0);
                    acc[mt][nt] = __builtin_amdgcn_mfma_f32_16x16x32_bf16(ah[mt], bl, acc[mt][nt], 0,0,0);
                    acc[mt][nt] = __builtin_amdgcn_mfma_f32_16x16x32_bf16(al[mt], bh, acc[mt][nt], 0,0,0);
                }
            }
        }
    };

    // input already staged by caller; leaves layer-2 raw acc for caller to finish
    auto eval = [&](const float* ttv){
        __syncthreads();                 // stage writes visible
        matmul(wpk);                     // layer 1
        __syncthreads();                 // all reads of input stage done
#pragma unroll
        for(int mt=0; mt<MT; mt++){
            const int db = 32*wvd + mt*16 + l4*4;
            f32x4 bv = *(const f32x4*)(b1 + db);
            f32x4 uv = *(const f32x4*)(u1 + db);
#pragma unroll
            for(int nt=0; nt<NT; nt++){
                float v[4];
#pragma unroll
                for(int r2=0;r2<4;r2++)
                    v[r2] = softplus_f(acc[mt][nt][r2] + bv[r2] + ttv[nt]*uv[r2]);
                put(mt, nt, v[0], v[1], v[2], v[3]);
            }
        }
        __syncthreads();
        matmul(wpk + 131072);            // layer 2
    };

    float s0 = 0.f;
#pragma unroll 1
    for(int step=0; step<3; step++){
        const float s1 = (step==0) ? 0.1127016653792583f : ((step==1) ? 0.5f : 0.8872983346207417f);
        const float gw = ((step==1) ? 0.88888f : 0.55555f) * 0.5f;
        const float dt = s1 - s0;
        const float c3 = dt * (1.f/3.f);
        const float dt8 = dt * 0.125f;
        float tt[NT];

        // ---- eval 1: f(s0, y) -> k1
        __syncthreads();                 // prior step's transpose reads done
#pragma unroll
        for(int mt=0; mt<MT; mt++)
#pragma unroll
            for(int nt=0; nt<NT; nt++)
                put(mt, nt, y[mt][nt][0], y[mt][nt][1], y[mt][nt][2], y[mt][nt][3]);
#pragma unroll
        for(int nt=0; nt<NT; nt++) tt[nt] = t0v[nt] + s0*rat[nt];
        eval(tt);

        // ---- k1 extract; stage y + (dt/3)k1
        __syncthreads();
#pragma unroll
        for(int mt=0; mt<MT; mt++){
            const int db = 32*wvd + mt*16 + l4*4;
            f32x4 bv = *(const f32x4*)(b2 + db);
            f32x4 uv = *(const f32x4*)(u2 + db);
#pragma unroll
            for(int nt=0; nt<NT; nt++){
                float v[4];
#pragma unroll
                for(int r2=0;r2<4;r2++){
                    float kk = (acc[mt][nt][r2] + bv[r2] + tt[nt]*uv[r2]) * rat[nt];
                    k1[mt][nt][r2] = kk;
                    v[r2] = fmaf(c3, kk, y[mt][nt][r2]);
                }
                put(mt, nt, v[0], v[1], v[2], v[3]);
            }
        }
#pragma unroll
        for(int nt=0; nt<NT; nt++) tt[nt] = t0v[nt] + (s0+c3)*rat[nt];
        eval(tt);

        // ---- k2 extract; stage y + dt*k2 - (dt/3)k1
        __syncthreads();
#pragma unroll
        for(int mt=0; mt<MT; mt++){
            const int db = 32*wvd + mt*16 + l4*4;
            f32x4 bv = *(const f32x4*)(b2 + db);
            f32x4 uv = *(const f32x4*)(u2 + db);
#pragma unroll
            for(int nt=0; nt<NT; nt++){
                float v[4];
#pragma unroll
                for(int r2=0;r2<4;r2++){
                    float kk = (acc[mt][nt][r2] + bv[r2] + tt[nt]*uv[r2]) * rat[nt];
                    k2[mt][nt][r2] = kk;
                    v[r2] = y[mt][nt][r2] + dt*kk - c3*k1[mt][nt][r2];
                }
                put(mt, nt, v[0], v[1], v[2], v[3]);
            }
        }
#pragma unroll
        for(int nt=0; nt<NT; nt++) tt[nt] = t0v[nt] + (s0+2.f*c3)*rat[nt];
        eval(tt);

        // ---- k3 extract (folded): stage y + dt*(k1-k2+k3); y += dt8*(k1+3(k2+k3))
        __syncthreads();
#pragma unroll
        for(int mt=0; mt<MT; mt++){
            const int db = 32*wvd + mt*16 + l4*4;
            f32x4 bv = *(const f32x4*)(b2 + db);
            f32x4 uv = *(const f32x4*)(u2 + db);
#pragma unroll
            for(int nt=0; nt<NT; nt++){
                float v[4];
#pragma unroll
                for(int r2=0;r2<4;r2++){
                    float k3v = (acc[mt][nt][r2] + bv[r2] + tt[nt]*uv[r2]) * rat[nt];
                    float yo = y[mt][nt][r2];
                    v[r2] = yo + dt*(k1[mt][nt][r2] - k2[mt][nt][r2] + k3v);
                    y[mt][nt][r2] = yo + dt8*(k1[mt][nt][r2] + 3.f*(k2[mt][nt][r2] + k3v));
                }
                put(mt, nt, v[0], v[1], v[2], v[3]);
            }
        }
#pragma unroll
        for(int nt=0; nt<NT; nt++) tt[nt] = t0v[nt] + s1*rat[nt];
        eval(tt);

        // ---- k4 fold, then transpose through LDS for coalesced output
        __syncthreads();                 // matmul2 reads of ylds done; safe to overwrite
        {
            float* yf = (float*)ylds;    // view: [64 rows][256 f32], 16B-granule swizzled
#pragma unroll
            for(int mt=0; mt<MT; mt++){
                const int db = 32*wvd + mt*16 + l4*4;
                f32x4 bv = *(const f32x4*)(b2 + db);
                f32x4 uv = *(const f32x4*)(u2 + db);
#pragma unroll
                for(int nt=0; nt<NT; nt++){
                    const int row = grp*32 + nt*16 + l15;
                    f32x4 ov;
#pragma unroll
                    for(int r2=0;r2<4;r2++){
                        float k4v = (acc[mt][nt][r2] + bv[r2] + tt[nt]*uv[r2]) * rat[nt];
                        float yn = fmaf(dt8, k4v, y[mt][nt][r2]);
                        y[mt][nt][r2] = yn;
                        ov[r2] = yn * gw;
                    }
                    const int c = 8*wvd + 4*mt + l4;         // logical 16B granule = d>>2
                    const int p = c ^ (row & 7);
                    *(f32x4*)&yf[row*256 + p*4] = ov;
                }
            }
            __syncthreads();
            // each wave stores 4 rows, 1KB contiguous per row — non-temporal
#pragma unroll
            for(int i=0;i<4;i++){
                const int r = 4*wv + i;
                f32x4 v = *(const f32x4*)&yf[r*256 + ((lane ^ (r&7))&63)*4];
                __builtin_nontemporal_store(v,
                    (f32x4*)(out + ((size_t)(base + r)*3 + step)*DM + lane*4));
            }
        }
        s0 = s1;
    }
}

extern "C" void kernel_launch(void* const* d_in, const int* in_sizes, int n_in,
                              void* d_out, int out_size, void* d_ws, size_t ws_size,
                              hipStream_t stream)
{
    const float* x  = (const float*)d_in[0];
    const float* t  = (const float*)d_in[1];
    const float* W1 = (const float*)d_in[2];
    const float* b1 = (const float*)d_in[3];
    const float* u1 = (const float*)d_in[4];
    const float* W2 = (const float*)d_in[5];
    const float* b2 = (const float*)d_in[6];
    const float* u2 = (const float*)d_in[7];
    ushort* wpk = (ushort*)d_ws;     // 512 KB: W1hi|W1lo|W2hi|W2lo packed fragments

    pack_w_kernel<<<dim3(256,2), 256, 0, stream>>>(W1, W2, wpk);
    ode_mfma_kernel<<<dim3((4*T_LEN*T_LEN)/NSAMP), 1024, 0, stream>>>(
        x, t, b1, u1, b2, u2, wpk, (float*)d_out);
}

// Round 8
// 1021.007 us; speedup vs baseline: 1.0052x; 1.0052x over previous
//
#include <hip/hip_runtime.h>

typedef float f32x4 __attribute__((ext_vector_type(4)));
typedef short bf16x8 __attribute__((ext_vector_type(8)));

#define T_LEN 96
#define DM    256
#define NSAMP 64      // ODE rows per block
#define MT 2          // d-tiles per wave (wave owns 32 d)
#define NT 2          // sample-tiles per wave (wave group owns 32 samples)

__device__ __forceinline__ uint bf16h(float x){            // f32 -> bf16 bits, RNE
    uint u = __float_as_uint(x);
    return (u + 0x7fffu + ((u>>16)&1u)) >> 16;
}
__device__ __forceinline__ float bf16f(uint h){ return __uint_as_float(h<<16); }
__device__ __forceinline__ float softplus_f(float x){
    return fmaxf(x,0.f) + log1pf(__expf(-fabsf(x)));
}

// Split W into bf16 hi/lo and pack into MFMA A-fragment order:
// frag (dt,ks): lane l holds W[dt*16 + (l&15)][ks*32 + (l>>4)*8 + i], i=0..7
// => packed[((dt*8+ks)*64 + l)*8 + i]; wave64 load = contiguous 1KB.
__global__ void pack_w_kernel(const float* __restrict__ W1, const float* __restrict__ W2,
                              ushort* __restrict__ ws){
    int idx = blockIdx.x*256 + threadIdx.x;          // 0..65535
    const float* W = blockIdx.y ? W2 : W1;
    ushort* hi = ws + (size_t)blockIdx.y*131072;     // [W1hi|W1lo|W2hi|W2lo], 65536 each
    ushort* lo = hi + 65536;
    float w = W[idx];
    uint h = bf16h(w);
    float l = w - bf16f(h);
    uint l16 = bf16h(l);
    int d = idx >> 8, k = idx & 255;
    int off = ((((d>>4)<<3) + (k>>5))<<9) + (((d&15) | (((k>>3)&3)<<4))<<3) + (k&7);
    hi[off] = (ushort)h;
    lo[off] = (ushort)l16;
}

// Register-budget control (the R4-R7 saga): the backend sets its VGPR target
// from the LDS-permitted occupancy, and __launch_bounds__' 2nd arg is only a
// MINIMUM waves/EU (64 VGPRs = 8 waves/EU satisfies "min 4" -> hint ignored,
// ~50 regs/thread spilled, 1.1GB of scratch HBM traffic). Two pins, same goal:
//   1) amdgpu_waves_per_eu(4,4): occupancy EXACTLY 4 waves/EU -> budget 128.
//   2) LDS padded 64KB -> 96KB: only 1 block/CU fits -> LDS-derived target is
//      itself 16 waves/CU = 4 waves/EU.
// Per-thread demand ~111 < 128 -> spill-free.
#define LDS_USHORTS (NSAMP*512)
#define LDS_PAD     16384            // pad to 96KB total

__global__ __launch_bounds__(1024)
__attribute__((amdgpu_waves_per_eu(4, 4)))
void ode_mfma_kernel(const float* __restrict__ x, const float* __restrict__ t,
                     const float* __restrict__ b1, const float* __restrict__ u1,
                     const float* __restrict__ b2, const float* __restrict__ u2,
                     const ushort* __restrict__ wpk, float* __restrict__ out)
{
    // Y stage: [row 0..63][hi 256 | lo 256] bf16; 16B granules XOR-swizzled by (row&7)
    __shared__ __align__(16) ushort ylds[LDS_USHORTS + LDS_PAD];

    const int tid  = threadIdx.x;
    const int wv   = tid >> 6;       // 0..15
    const int wvd  = wv & 7;         // d-slice owner
    const int grp  = wv >> 3;        // sample group
    const int lane = tid & 63;
    const int l15  = lane & 15;
    const int l4   = lane >> 4;
    const int base = blockIdx.x * NSAMP;

    float t0v[NT], rat[NT];
    float y[MT][NT][4], k1[MT][NT][4], k2[MT][NT][4];
    f32x4 acc[MT][NT];

#pragma unroll
    for(int nt=0; nt<NT; nt++){
        int n = base + grp*32 + nt*16 + l15;
        int b = n / (T_LEN*T_LEN);
        int r = n - b*(T_LEN*T_LEN);
        int q = r / T_LEN;
        int j = r - q*T_LEN;
        float ta = t[b*T_LEN + j], tb = t[b*T_LEN + q];
        t0v[nt] = ta; rat[nt] = tb - ta;
        const float* xr = x + (size_t)(b*T_LEN + j)*DM;
#pragma unroll
        for(int mt=0; mt<MT; mt++){
            const int db = 32*wvd + mt*16 + l4*4;
            f32x4 v = *(const f32x4*)(xr + db);
#pragma unroll
            for(int r2=0;r2<4;r2++) y[mt][nt][r2] = v[r2];
        }
    }

    // write 4 consecutive-d values (one D-fragment reg group) as hi/lo bf16 into ylds
    auto put = [&](int mt, int nt, float v0, float v1, float v2, float v3){
        uint h0=bf16h(v0), h1=bf16h(v1), h2=bf16h(v2), h3=bf16h(v3);
        uint hp0 = h0 | (h1<<16), hp1 = h2 | (h3<<16);
        uint lp0 = bf16h(v0 - bf16f(h0)) | (bf16h(v1 - bf16f(h1))<<16);
        uint lp1 = bf16h(v2 - bf16f(h2)) | (bf16h(v3 - bf16f(h3))<<16);
        int row = grp*32 + nt*16 + l15;
        int col = 4*wvd + 2*mt + (l4>>1);       // logical 16B granule (8 k)
        int g   = col ^ (row & 7);              // swizzle low 3 granule bits
        int idx = row*512 + g*8 + (l4&1)*4;
        *(uint2*)&ylds[idx]       = make_uint2(hp0, hp1);   // hi half
        *(uint2*)&ylds[idx + 256] = make_uint2(lp0, lp1);   // lo half
    };

    // acc[mt][nt] = (W-slice) x Y^T over K=256, 3-product bf16 split
    auto matmul = [&](const ushort* Whi){
        const ushort* Wlo = Whi + 65536;
#pragma unroll
        for(int mt=0; mt<MT; mt++)
#pragma unroll
            for(int nt=0; nt<NT; nt++)
                acc[mt][nt] = (f32x4){0.f,0.f,0.f,0.f};
#pragma unroll 2
        for(int ks=0; ks<8; ks++){
            bf16x8 ah[MT], al[MT];
#pragma unroll
            for(int mt=0; mt<MT; mt++){
                const int off = ((((2*wvd+mt)<<3)+ks)<<9) + (lane<<3);
                ah[mt] = *(const bf16x8*)(Whi + off);
                al[mt] = *(const bf16x8*)(Wlo + off);
            }
#pragma unroll
            for(int nt=0; nt<NT; nt++){
                const int row = grp*32 + nt*16 + l15;
                const int gx  = (ks*4 + l4) ^ (row & 7);
                const ushort* bp = &ylds[row*512 + gx*8];
                bf16x8 bh = *(const bf16x8*)bp;
                bf16x8 bl = *(const bf16x8*)(bp + 256);
#pragma unroll
                for(int mt=0; mt<MT; mt++){
                    acc[mt][nt] = __builtin_amdgcn_mfma_f32_16x16x32_bf16(ah[mt], bh, acc[mt][nt], 0,0,0);
                    acc[mt][nt] = __builtin_amdgcn_mfma_f32_16x16x32_bf16(ah[mt], bl, acc[mt][nt], 0,0,0);
                    acc[mt][nt] = __builtin_amdgcn_mfma_f32_16x16x32_bf16(al[mt], bh, acc[mt][nt], 0,0,0);
                }
            }
        }
    };

    // input already staged by caller; leaves layer-2 raw acc for caller to finish
    auto eval = [&](const float* ttv){
        __syncthreads();                 // stage writes visible
        matmul(wpk);                     // layer 1
        __syncthreads();                 // all reads of input stage done
#pragma unroll
        for(int mt=0; mt<MT; mt++){
            const int db = 32*wvd + mt*16 + l4*4;
            f32x4 bv = *(const f32x4*)(b1 + db);
            f32x4 uv = *(const f32x4*)(u1 + db);
#pragma unroll
            for(int nt=0; nt<NT; nt++){
                float v[4];
#pragma unroll
                for(int r2=0;r2<4;r2++)
                    v[r2] = softplus_f(acc[mt][nt][r2] + bv[r2] + ttv[nt]*uv[r2]);
                put(mt, nt, v[0], v[1], v[2], v[3]);
            }
        }
        __syncthreads();
        matmul(wpk + 131072);            // layer 2
    };

    float s0 = 0.f;
#pragma unroll 1
    for(int step=0; step<3; step++){
        const float s1 = (step==0) ? 0.1127016653792583f : ((step==1) ? 0.5f : 0.8872983346207417f);
        const float gw = ((step==1) ? 0.88888f : 0.55555f) * 0.5f;
        const float dt = s1 - s0;
        const float c3 = dt * (1.f/3.f);
        const float dt8 = dt * 0.125f;
        float tt[NT];

        // ---- eval 1: f(s0, y) -> k1
        __syncthreads();                 // prior step's transpose reads done
#pragma unroll
        for(int mt=0; mt<MT; mt++)
#pragma unroll
            for(int nt=0; nt<NT; nt++)
                put(mt, nt, y[mt][nt][0], y[mt][nt][1], y[mt][nt][2], y[mt][nt][3]);
#pragma unroll
        for(int nt=0; nt<NT; nt++) tt[nt] = t0v[nt] + s0*rat[nt];
        eval(tt);

        // ---- k1 extract; stage y + (dt/3)k1
        __syncthreads();
#pragma unroll
        for(int mt=0; mt<MT; mt++){
            const int db = 32*wvd + mt*16 + l4*4;
            f32x4 bv = *(const f32x4*)(b2 + db);
            f32x4 uv = *(const f32x4*)(u2 + db);
#pragma unroll
            for(int nt=0; nt<NT; nt++){
                float v[4];
#pragma unroll
                for(int r2=0;r2<4;r2++){
                    float kk = (acc[mt][nt][r2] + bv[r2] + tt[nt]*uv[r2]) * rat[nt];
                    k1[mt][nt][r2] = kk;
                    v[r2] = fmaf(c3, kk, y[mt][nt][r2]);
                }
                put(mt, nt, v[0], v[1], v[2], v[3]);
            }
        }
#pragma unroll
        for(int nt=0; nt<NT; nt++) tt[nt] = t0v[nt] + (s0+c3)*rat[nt];
        eval(tt);

        // ---- k2 extract; stage y + dt*k2 - (dt/3)k1
        __syncthreads();
#pragma unroll
        for(int mt=0; mt<MT; mt++){
            const int db = 32*wvd + mt*16 + l4*4;
            f32x4 bv = *(const f32x4*)(b2 + db);
            f32x4 uv = *(const f32x4*)(u2 + db);
#pragma unroll
            for(int nt=0; nt<NT; nt++){
                float v[4];
#pragma unroll
                for(int r2=0;r2<4;r2++){
                    float kk = (acc[mt][nt][r2] + bv[r2] + tt[nt]*uv[r2]) * rat[nt];
                    k2[mt][nt][r2] = kk;
                    v[r2] = y[mt][nt][r2] + dt*kk - c3*k1[mt][nt][r2];
                }
                put(mt, nt, v[0], v[1], v[2], v[3]);
            }
        }
#pragma unroll
        for(int nt=0; nt<NT; nt++) tt[nt] = t0v[nt] + (s0+2.f*c3)*rat[nt];
        eval(tt);

        // ---- k3 extract (folded): stage y + dt*(k1-k2+k3); y += dt8*(k1+3(k2+k3))
        __syncthreads();
#pragma unroll
        for(int mt=0; mt<MT; mt++){
            const int db = 32*wvd + mt*16 + l4*4;
            f32x4 bv = *(const f32x4*)(b2 + db);
            f32x4 uv = *(const f32x4*)(u2 + db);
#pragma unroll
            for(int nt=0; nt<NT; nt++){
                float v[4];
#pragma unroll
                for(int r2=0;r2<4;r2++){
                    float k3v = (acc[mt][nt][r2] + bv[r2] + tt[nt]*uv[r2]) * rat[nt];
                    float yo = y[mt][nt][r2];
                    v[r2] = yo + dt*(k1[mt][nt][r2] - k2[mt][nt][r2] + k3v);
                    y[mt][nt][r2] = yo + dt8*(k1[mt][nt][r2] + 3.f*(k2[mt][nt][r2] + k3v));
                }
                put(mt, nt, v[0], v[1], v[2], v[3]);
            }
        }
#pragma unroll
        for(int nt=0; nt<NT; nt++) tt[nt] = t0v[nt] + s1*rat[nt];
        eval(tt);

        // ---- k4 fold, then transpose through LDS for coalesced output
        __syncthreads();                 // matmul2 reads of ylds done; safe to overwrite
        {
            float* yf = (float*)ylds;    // view: [64 rows][256 f32], 16B-granule swizzled
#pragma unroll
            for(int mt=0; mt<MT; mt++){
                const int db = 32*wvd + mt*16 + l4*4;
                f32x4 bv = *(const f32x4*)(b2 + db);
                f32x4 uv = *(const f32x4*)(u2 + db);
#pragma unroll
                for(int nt=0; nt<NT; nt++){
                    const int row = grp*32 + nt*16 + l15;
                    f32x4 ov;
#pragma unroll
                    for(int r2=0;r2<4;r2++){
                        float k4v = (acc[mt][nt][r2] + bv[r2] + tt[nt]*uv[r2]) * rat[nt];
                        float yn = fmaf(dt8, k4v, y[mt][nt][r2]);
                        y[mt][nt][r2] = yn;
                        ov[r2] = yn * gw;
                    }
                    const int c = 8*wvd + 4*mt + l4;         // logical 16B granule = d>>2
                    const int p = c ^ (row & 7);
                    *(f32x4*)&yf[row*256 + p*4] = ov;
                }
            }
            __syncthreads();
            // each wave stores 4 rows, 1KB contiguous per row — non-temporal
#pragma unroll
            for(int i=0;i<4;i++){
                const int r = 4*wv + i;
                f32x4 v = *(const f32x4*)&yf[r*256 + ((lane ^ (r&7))&63)*4];
                __builtin_nontemporal_store(v,
                    (f32x4*)(out + ((size_t)(base + r)*3 + step)*DM + lane*4));
            }
        }
        s0 = s1;
    }
}

extern "C" void kernel_launch(void* const* d_in, const int* in_sizes, int n_in,
                              void* d_out, int out_size, void* d_ws, size_t ws_size,
                              hipStream_t stream)
{
    const float* x  = (const float*)d_in[0];
    const float* t  = (const float*)d_in[1];
    const float* W1 = (const float*)d_in[2];
    const float* b1 = (const float*)d_in[3];
    const float* u1 = (const float*)d_in[4];
    const float* W2 = (const float*)d_in[5];
    const float* b2 = (const float*)d_in[6];
    const float* u2 = (const float*)d_in[7];
    ushort* wpk = (ushort*)d_ws;     // 512 KB: W1hi|W1lo|W2hi|W2lo packed fragments

    pack_w_kernel<<<dim3(256,2), 256, 0, stream>>>(W1, W2, wpk);
    ode_mfma_kernel<<<dim3((4*T_LEN*T_LEN)/NSAMP), 1024, 0, stream>>>(
        x, t, b1, u1, b2, u2, wpk, (float*)d_out);
}

// Round 9
// 629.191 us; speedup vs baseline: 1.6311x; 1.6227x over previous
//
#include <hip/hip_runtime.h>

typedef float f32x4 __attribute__((ext_vector_type(4)));
typedef short bf16x8 __attribute__((ext_vector_type(8)));

#define T_LEN 96
#define DM    256
#define NSAMP 32      // ODE rows per block
#define MT 2          // d-tiles per wave (wave owns 32 d)
#define NT 2          // sample-tiles per wave (wave owns all 32 samples)

__device__ __forceinline__ uint bf16h(float x){            // f32 -> bf16 bits, RNE
    uint u = __float_as_uint(x);
    return (u + 0x7fffu + ((u>>16)&1u)) >> 16;
}
__device__ __forceinline__ float bf16f(uint h){ return __uint_as_float(h<<16); }
__device__ __forceinline__ float softplus_f(float x){
    return fmaxf(x,0.f) + log1pf(__expf(-fabsf(x)));
}

// Split W into bf16 hi/lo and pack into MFMA A-fragment order:
// frag (dt,ks): lane l holds W[dt*16 + (l&15)][ks*32 + (l>>4)*8 + i], i=0..7
// => packed[((dt*8+ks)*64 + l)*8 + i]; wave64 load = contiguous 1KB.
__global__ void pack_w_kernel(const float* __restrict__ W1, const float* __restrict__ W2,
                              ushort* __restrict__ ws){
    int idx = blockIdx.x*256 + threadIdx.x;          // 0..65535
    const float* W = blockIdx.y ? W2 : W1;
    ushort* hi = ws + (size_t)blockIdx.y*131072;     // [W1hi|W1lo|W2hi|W2lo], 65536 each
    ushort* lo = hi + 65536;
    float w = W[idx];
    uint h = bf16h(w);
    float l = w - bf16f(h);
    uint l16 = bf16h(l);
    int d = idx >> 8, k = idx & 255;
    int off = ((((d>>4)<<3) + (k>>5))<<9) + (((d&15) | (((k>>3)&3)<<4))<<3) + (k&7);
    hi[off] = (ushort)h;
    lo[off] = (ushort)l16;
}

// Register-budget saga (R4-R8): with 1024-thr blocks the backend pins 64
// arch-VGPRs (spilling ~1.1GB of scratch HBM traffic) and ignores
// __launch_bounds__ min-waves AND amdgpu_waves_per_eu. With 512-thr blocks
// (R5) it chooses 128. So: 512 threads, and per-thread demand cut to ~110
// (NT=2 -> y/k1/k2 = 48 f32) < 128 -> spill-free. LDS padded to 56KB keeps
// the LDS-derived occupancy target at 2 blocks/CU = 4 waves/EU (budget 128).
#define LDS_USHORTS (NSAMP*512)
#define LDS_PAD     12288            // 32KB + 24KB = 56KB total

__global__ __launch_bounds__(512)
void ode_mfma_kernel(const float* __restrict__ x, const float* __restrict__ t,
                     const float* __restrict__ b1, const float* __restrict__ u1,
                     const float* __restrict__ b2, const float* __restrict__ u2,
                     const ushort* __restrict__ wpk, float* __restrict__ out)
{
    // Y stage: [row 0..31][hi 256 | lo 256] bf16; 16B granules XOR-swizzled by (row&7)
    __shared__ __align__(16) ushort ylds[LDS_USHORTS + LDS_PAD];

    const int tid  = threadIdx.x;
    const int wvd  = tid >> 6;       // wave 0..7 owns d in [32*wvd, 32*wvd+32)
    const int lane = tid & 63;
    const int l15  = lane & 15;
    const int l4   = lane >> 4;
    const int base = blockIdx.x * NSAMP;

    float t0v[NT], rat[NT];
    float y[MT][NT][4], k1[MT][NT][4], k2[MT][NT][4];
    f32x4 acc[MT][NT];

#pragma unroll
    for(int nt=0; nt<NT; nt++){
        int n = base + nt*16 + l15;
        int b = n / (T_LEN*T_LEN);
        int r = n - b*(T_LEN*T_LEN);
        int q = r / T_LEN;
        int j = r - q*T_LEN;
        float ta = t[b*T_LEN + j], tb = t[b*T_LEN + q];
        t0v[nt] = ta; rat[nt] = tb - ta;
        const float* xr = x + (size_t)(b*T_LEN + j)*DM;
#pragma unroll
        for(int mt=0; mt<MT; mt++){
            const int db = 32*wvd + mt*16 + l4*4;
            f32x4 v = *(const f32x4*)(xr + db);
#pragma unroll
            for(int r2=0;r2<4;r2++) y[mt][nt][r2] = v[r2];
        }
    }

    // write 4 consecutive-d values (one D-fragment reg group) as hi/lo bf16 into ylds
    auto put = [&](int mt, int nt, float v0, float v1, float v2, float v3){
        uint h0=bf16h(v0), h1=bf16h(v1), h2=bf16h(v2), h3=bf16h(v3);
        uint hp0 = h0 | (h1<<16), hp1 = h2 | (h3<<16);
        uint lp0 = bf16h(v0 - bf16f(h0)) | (bf16h(v1 - bf16f(h1))<<16);
        uint lp1 = bf16h(v2 - bf16f(h2)) | (bf16h(v3 - bf16f(h3))<<16);
        int row = nt*16 + l15;
        int col = 4*wvd + 2*mt + (l4>>1);       // logical 16B granule (8 k)
        int g   = col ^ (row & 7);              // swizzle low 3 granule bits
        int idx = row*512 + g*8 + (l4&1)*4;
        *(uint2*)&ylds[idx]       = make_uint2(hp0, hp1);   // hi half
        *(uint2*)&ylds[idx + 256] = make_uint2(lp0, lp1);   // lo half
    };

    // acc[mt][nt] = (W-slice) x Y^T over K=256, 3-product bf16 split
    auto matmul = [&](const ushort* Whi){
        const ushort* Wlo = Whi + 65536;
#pragma unroll
        for(int mt=0; mt<MT; mt++)
#pragma unroll
            for(int nt=0; nt<NT; nt++)
                acc[mt][nt] = (f32x4){0.f,0.f,0.f,0.f};
#pragma unroll 2
        for(int ks=0; ks<8; ks++){
            bf16x8 ah[MT], al[MT];
#pragma unroll
            for(int mt=0; mt<MT; mt++){
                const int off = ((((2*wvd+mt)<<3)+ks)<<9) + (lane<<3);
                ah[mt] = *(const bf16x8*)(Whi + off);
                al[mt] = *(const bf16x8*)(Wlo + off);
            }
#pragma unroll
            for(int nt=0; nt<NT; nt++){
                const int row = nt*16 + l15;
                const int gx  = (ks*4 + l4) ^ (row & 7);
                const ushort* bp = &ylds[row*512 + gx*8];
                bf16x8 bh = *(const bf16x8*)bp;
                bf16x8 bl = *(const bf16x8*)(bp + 256);
#pragma unroll
                for(int mt=0; mt<MT; mt++){
                    acc[mt][nt] = __builtin_amdgcn_mfma_f32_16x16x32_bf16(ah[mt], bh, acc[mt][nt], 0,0,0);
                    acc[mt][nt] = __builtin_amdgcn_mfma_f32_16x16x32_bf16(ah[mt], bl, acc[mt][nt], 0,0,0);
                    acc[mt][nt] = __builtin_amdgcn_mfma_f32_16x16x32_bf16(al[mt], bh, acc[mt][nt], 0,0,0);
                }
            }
        }
    };

    // input already staged by caller; leaves layer-2 raw acc for caller to finish
    auto eval = [&](const float* ttv){
        __syncthreads();                 // stage writes visible
        matmul(wpk);                     // layer 1
        __syncthreads();                 // all reads of input stage done
#pragma unroll
        for(int mt=0; mt<MT; mt++){
            const int db = 32*wvd + mt*16 + l4*4;
            f32x4 bv = *(const f32x4*)(b1 + db);
            f32x4 uv = *(const f32x4*)(u1 + db);
#pragma unroll
            for(int nt=0; nt<NT; nt++){
                float v[4];
#pragma unroll
                for(int r2=0;r2<4;r2++)
                    v[r2] = softplus_f(acc[mt][nt][r2] + bv[r2] + ttv[nt]*uv[r2]);
                put(mt, nt, v[0], v[1], v[2], v[3]);
            }
        }
        __syncthreads();
        matmul(wpk + 131072);            // layer 2
    };

    float s0 = 0.f;
#pragma unroll 1
    for(int step=0; step<3; step++){
        const float s1 = (step==0) ? 0.1127016653792583f : ((step==1) ? 0.5f : 0.8872983346207417f);
        const float gw = ((step==1) ? 0.88888f : 0.55555f) * 0.5f;
        const float dt = s1 - s0;
        const float c3 = dt * (1.f/3.f);
        const float dt8 = dt * 0.125f;
        float tt[NT];

        // ---- eval 1: f(s0, y) -> k1
        __syncthreads();                 // prior step's transpose reads done
#pragma unroll
        for(int mt=0; mt<MT; mt++)
#pragma unroll
            for(int nt=0; nt<NT; nt++)
                put(mt, nt, y[mt][nt][0], y[mt][nt][1], y[mt][nt][2], y[mt][nt][3]);
#pragma unroll
        for(int nt=0; nt<NT; nt++) tt[nt] = t0v[nt] + s0*rat[nt];
        eval(tt);

        // ---- k1 extract; stage y + (dt/3)k1
        __syncthreads();
#pragma unroll
        for(int mt=0; mt<MT; mt++){
            const int db = 32*wvd + mt*16 + l4*4;
            f32x4 bv = *(const f32x4*)(b2 + db);
            f32x4 uv = *(const f32x4*)(u2 + db);
#pragma unroll
            for(int nt=0; nt<NT; nt++){
                float v[4];
#pragma unroll
                for(int r2=0;r2<4;r2++){
                    float kk = (acc[mt][nt][r2] + bv[r2] + tt[nt]*uv[r2]) * rat[nt];
                    k1[mt][nt][r2] = kk;
                    v[r2] = fmaf(c3, kk, y[mt][nt][r2]);
                }
                put(mt, nt, v[0], v[1], v[2], v[3]);
            }
        }
#pragma unroll
        for(int nt=0; nt<NT; nt++) tt[nt] = t0v[nt] + (s0+c3)*rat[nt];
        eval(tt);

        // ---- k2 extract; stage y + dt*k2 - (dt/3)k1
        __syncthreads();
#pragma unroll
        for(int mt=0; mt<MT; mt++){
            const int db = 32*wvd + mt*16 + l4*4;
            f32x4 bv = *(const f32x4*)(b2 + db);
            f32x4 uv = *(const f32x4*)(u2 + db);
#pragma unroll
            for(int nt=0; nt<NT; nt++){
                float v[4];
#pragma unroll
                for(int r2=0;r2<4;r2++){
                    float kk = (acc[mt][nt][r2] + bv[r2] + tt[nt]*uv[r2]) * rat[nt];
                    k2[mt][nt][r2] = kk;
                    v[r2] = y[mt][nt][r2] + dt*kk - c3*k1[mt][nt][r2];
                }
                put(mt, nt, v[0], v[1], v[2], v[3]);
            }
        }
#pragma unroll
        for(int nt=0; nt<NT; nt++) tt[nt] = t0v[nt] + (s0+2.f*c3)*rat[nt];
        eval(tt);

        // ---- k3 extract (folded): stage y + dt*(k1-k2+k3); y += dt8*(k1+3(k2+k3))
        __syncthreads();
#pragma unroll
        for(int mt=0; mt<MT; mt++){
            const int db = 32*wvd + mt*16 + l4*4;
            f32x4 bv = *(const f32x4*)(b2 + db);
            f32x4 uv = *(const f32x4*)(u2 + db);
#pragma unroll
            for(int nt=0; nt<NT; nt++){
                float v[4];
#pragma unroll
                for(int r2=0;r2<4;r2++){
                    float k3v = (acc[mt][nt][r2] + bv[r2] + tt[nt]*uv[r2]) * rat[nt];
                    float yo = y[mt][nt][r2];
                    v[r2] = yo + dt*(k1[mt][nt][r2] - k2[mt][nt][r2] + k3v);
                    y[mt][nt][r2] = yo + dt8*(k1[mt][nt][r2] + 3.f*(k2[mt][nt][r2] + k3v));
                }
                put(mt, nt, v[0], v[1], v[2], v[3]);
            }
        }
#pragma unroll
        for(int nt=0; nt<NT; nt++) tt[nt] = t0v[nt] + s1*rat[nt];
        eval(tt);

        // ---- k4 fold, then transpose through LDS for coalesced output
        __syncthreads();                 // matmul2 reads of ylds done; safe to overwrite
        {
            float* yf = (float*)ylds;    // view: [32 rows][256 f32], 16B-granule swizzled
#pragma unroll
            for(int mt=0; mt<MT; mt++){
                const int db = 32*wvd + mt*16 + l4*4;
                f32x4 bv = *(const f32x4*)(b2 + db);
                f32x4 uv = *(const f32x4*)(u2 + db);
#pragma unroll
                for(int nt=0; nt<NT; nt++){
                    const int row = nt*16 + l15;
                    f32x4 ov;
#pragma unroll
                    for(int r2=0;r2<4;r2++){
                        float k4v = (acc[mt][nt][r2] + bv[r2] + tt[nt]*uv[r2]) * rat[nt];
                        float yn = fmaf(dt8, k4v, y[mt][nt][r2]);
                        y[mt][nt][r2] = yn;
                        ov[r2] = yn * gw;
                    }
                    const int c = 8*wvd + 4*mt + l4;         // logical 16B granule = d>>2
                    const int p = c ^ (row & 7);
                    *(f32x4*)&yf[row*256 + p*4] = ov;
                }
            }
            __syncthreads();
            // each wave stores 4 rows, 1KB contiguous per row — non-temporal
#pragma unroll
            for(int i=0;i<4;i++){
                const int r = 4*wvd + i;
                f32x4 v = *(const f32x4*)&yf[r*256 + ((lane ^ (r&7))&63)*4];
                __builtin_nontemporal_store(v,
                    (f32x4*)(out + ((size_t)(base + r)*3 + step)*DM + lane*4));
            }
        }
        s0 = s1;
    }
}

extern "C" void kernel_launch(void* const* d_in, const int* in_sizes, int n_in,
                              void* d_out, int out_size, void* d_ws, size_t ws_size,
                              hipStream_t stream)
{
    const float* x  = (const float*)d_in[0];
    const float* t  = (const float*)d_in[1];
    const float* W1 = (const float*)d_in[2];
    const float* b1 = (const float*)d_in[3];
    const float* u1 = (const float*)d_in[4];
    const float* W2 = (const float*)d_in[5];
    const float* b2 = (const float*)d_in[6];
    const float* u2 = (const float*)d_in[7];
    ushort* wpk = (ushort*)d_ws;     // 512 KB: W1hi|W1lo|W2hi|W2lo packed fragments

    pack_w_kernel<<<dim3(256,2), 256, 0, stream>>>(W1, W2, wpk);
    ode_mfma_kernel<<<dim3((4*T_LEN*T_LEN)/NSAMP), 512, 0, stream>>>(
        x, t, b1, u1, b2, u2, wpk, (float*)d_out);
}

// Round 10
// 415.223 us; speedup vs baseline: 2.4717x; 1.5153x over previous
//
#include <hip/hip_runtime.h>

typedef float f32x4 __attribute__((ext_vector_type(4)));
typedef short bf16x8 __attribute__((ext_vector_type(8)));

#define T_LEN 96
#define DM    256
#define NSAMP 32      // ODE rows per block
#define MT 2          // d-tiles per wave (wave owns 32 d)
#define NT 2          // sample-tiles per wave (wave owns all 32 samples)
#define BUF_USH 16384 // 32 rows * 512 ushorts per stage buffer

__device__ __forceinline__ uint bf16h(float x){            // f32 -> bf16 bits, RNE
    uint u = __float_as_uint(x);
    return (u + 0x7fffu + ((u>>16)&1u)) >> 16;
}
__device__ __forceinline__ float bf16f(uint h){ return __uint_as_float(h<<16); }

// packed bf16 pair via HW convert (RNE), 1 instr vs ~8 of bit-twiddling
__device__ __forceinline__ uint cvtpk(float a, float b){
    uint r; asm("v_cvt_pk_bf16_f32 %0, %1, %2" : "=v"(r) : "v"(a), "v"(b)); return r;
}
// fast softplus: ~8 instr (2 trans ops) vs log1pf's ~25-instr libm expansion.
// |err| ~1e-7 abs, threshold is 3.9e-2.
__device__ __forceinline__ float softplus_f(float x){
    float u = __expf(-fabsf(x));
    return fmaxf(x, 0.f) + __logf(1.0f + u);
}

// Split W into bf16 hi/lo and pack into MFMA A-fragment order:
// frag (dt,ks): lane l holds W[dt*16 + (l&15)][ks*32 + (l>>4)*8 + i], i=0..7
// => packed[((dt*8+ks)*64 + l)*8 + i]; wave64 load = contiguous 1KB.
__global__ void pack_w_kernel(const float* __restrict__ W1, const float* __restrict__ W2,
                              ushort* __restrict__ ws){
    int idx = blockIdx.x*256 + threadIdx.x;          // 0..65535
    const float* W = blockIdx.y ? W2 : W1;
    ushort* hi = ws + (size_t)blockIdx.y*131072;     // [W1hi|W1lo|W2hi|W2lo], 65536 each
    ushort* lo = hi + 65536;
    float w = W[idx];
    uint h = bf16h(w);
    float l = w - bf16f(h);
    uint l16 = bf16h(l);
    int d = idx >> 8, k = idx & 255;
    int off = ((((d>>4)<<3) + (k>>5))<<9) + (((d&15) | (((k>>3)&3)<<4))<<3) + (k&7);
    hi[off] = (ushort)h;
    lo[off] = (ushort)l16;
}

// R9 config (R4-R8 saga): 512 thr + LDS in (53.3KB, 80KB] keeps the backend's
// occupancy target at 2 blocks/CU = 4 waves/EU -> 128-VGPR budget; per-thread
// demand ~110 -> spill-free (VGPR_Count 116, FETCH collapsed 587MB->4MB).
// R10: double-buffered stage (buf0 = ODE state for layer1, buf1 = hidden for
// layer2) -> 2 barriers/eval instead of 4; LDS = 64KB exactly, same window.
__global__ __launch_bounds__(512)
void ode_mfma_kernel(const float* __restrict__ x, const float* __restrict__ t,
                     const float* __restrict__ b1, const float* __restrict__ u1,
                     const float* __restrict__ b2, const float* __restrict__ u2,
                     const ushort* __restrict__ wpk, float* __restrict__ out)
{
    // two stage buffers: [buf][row 0..31][hi 256 | lo 256] bf16,
    // 16B granules XOR-swizzled by (row&7)
    __shared__ __align__(16) ushort ylds[2*BUF_USH];

    const int tid  = threadIdx.x;
    const int wvd  = tid >> 6;       // wave 0..7 owns d in [32*wvd, 32*wvd+32)
    const int lane = tid & 63;
    const int l15  = lane & 15;
    const int l4   = lane >> 4;
    const int base = blockIdx.x * NSAMP;

    float t0v[NT], rat[NT];
    float y[MT][NT][4], k1[MT][NT][4], k2[MT][NT][4];
    f32x4 acc[MT][NT];

#pragma unroll
    for(int nt=0; nt<NT; nt++){
        int n = base + nt*16 + l15;
        int b = n / (T_LEN*T_LEN);
        int r = n - b*(T_LEN*T_LEN);
        int q = r / T_LEN;
        int j = r - q*T_LEN;
        float ta = t[b*T_LEN + j], tb = t[b*T_LEN + q];
        t0v[nt] = ta; rat[nt] = tb - ta;
        const float* xr = x + (size_t)(b*T_LEN + j)*DM;
#pragma unroll
        for(int mt=0; mt<MT; mt++){
            const int db = 32*wvd + mt*16 + l4*4;
            f32x4 v = *(const f32x4*)(xr + db);
#pragma unroll
            for(int r2=0;r2<4;r2++) y[mt][nt][r2] = v[r2];
        }
    }

    // write 4 consecutive-d values as hi/lo bf16 into stage buffer `buf`
    auto put = [&](int buf, int mt, int nt, float v0, float v1, float v2, float v3){
        uint hp0 = cvtpk(v0, v1), hp1 = cvtpk(v2, v3);
        float h0 = __uint_as_float(hp0<<16), h1 = __uint_as_float(hp0 & 0xffff0000u);
        float h2 = __uint_as_float(hp1<<16), h3 = __uint_as_float(hp1 & 0xffff0000u);
        uint lp0 = cvtpk(v0-h0, v1-h1), lp1 = cvtpk(v2-h2, v3-h3);
        int row = nt*16 + l15;
        int col = 4*wvd + 2*mt + (l4>>1);       // logical 16B granule (8 k)
        int g   = col ^ (row & 7);              // swizzle low 3 granule bits
        int idx = buf*BUF_USH + row*512 + g*8 + (l4&1)*4;
        *(uint2*)&ylds[idx]       = make_uint2(hp0, hp1);   // hi half
        *(uint2*)&ylds[idx + 256] = make_uint2(lp0, lp1);   // lo half
    };

    // acc[mt][nt] = (W-slice) x Y^T over K=256, 3-product bf16 split
    auto matmul = [&](const ushort* Whi, int buf){
        const ushort* Wlo = Whi + 65536;
        const int bbase = buf*BUF_USH;
#pragma unroll
        for(int mt=0; mt<MT; mt++)
#pragma unroll
            for(int nt=0; nt<NT; nt++)
                acc[mt][nt] = (f32x4){0.f,0.f,0.f,0.f};
#pragma unroll 2
        for(int ks=0; ks<8; ks++){
            bf16x8 ah[MT], al[MT];
#pragma unroll
            for(int mt=0; mt<MT; mt++){
                const int off = ((((2*wvd+mt)<<3)+ks)<<9) + (lane<<3);
                ah[mt] = *(const bf16x8*)(Whi + off);
                al[mt] = *(const bf16x8*)(Wlo + off);
            }
#pragma unroll
            for(int nt=0; nt<NT; nt++){
                const int row = nt*16 + l15;
                const int gx  = (ks*4 + l4) ^ (row & 7);
                const ushort* bp = &ylds[bbase + row*512 + gx*8];
                bf16x8 bh = *(const bf16x8*)bp;
                bf16x8 bl = *(const bf16x8*)(bp + 256);
#pragma unroll
                for(int mt=0; mt<MT; mt++){
                    acc[mt][nt] = __builtin_amdgcn_mfma_f32_16x16x32_bf16(ah[mt], bh, acc[mt][nt], 0,0,0);
                    acc[mt][nt] = __builtin_amdgcn_mfma_f32_16x16x32_bf16(ah[mt], bl, acc[mt][nt], 0,0,0);
                    acc[mt][nt] = __builtin_amdgcn_mfma_f32_16x16x32_bf16(al[mt], bh, acc[mt][nt], 0,0,0);
                }
            }
        }
    };

    // input staged in buf0 by caller; leaves layer-2 raw acc for caller
    auto eval = [&](const float* ttv){
        __syncthreads();                 // all puts to buf0 done
        matmul(wpk, 0);                  // layer 1 reads buf0
        // write hidden into buf1 — other waves at worst still read buf0
#pragma unroll
        for(int mt=0; mt<MT; mt++){
            const int db = 32*wvd + mt*16 + l4*4;
            f32x4 bv = *(const f32x4*)(b1 + db);
            f32x4 uv = *(const f32x4*)(u1 + db);
#pragma unroll
            for(int nt=0; nt<NT; nt++){
                float v[4];
#pragma unroll
                for(int r2=0;r2<4;r2++)
                    v[r2] = softplus_f(acc[mt][nt][r2] + bv[r2] + ttv[nt]*uv[r2]);
                put(1, mt, nt, v[0], v[1], v[2], v[3]);
            }
        }
        __syncthreads();                 // all puts to buf1 done
        matmul(wpk + 131072, 1);         // layer 2 reads buf1
        // caller's extract-put targets buf0 — other waves at worst read buf1
    };

    float s0 = 0.f;
#pragma unroll 1
    for(int step=0; step<3; step++){
        const float s1 = (step==0) ? 0.1127016653792583f : ((step==1) ? 0.5f : 0.8872983346207417f);
        const float gw = ((step==1) ? 0.88888f : 0.55555f) * 0.5f;
        const float dt = s1 - s0;
        const float c3 = dt * (1.f/3.f);
        const float dt8 = dt * 0.125f;
        float tt[NT];

        // ---- eval 1: f(s0, y) -> k1   (stage y into buf0)
#pragma unroll
        for(int mt=0; mt<MT; mt++)
#pragma unroll
            for(int nt=0; nt<NT; nt++)
                put(0, mt, nt, y[mt][nt][0], y[mt][nt][1], y[mt][nt][2], y[mt][nt][3]);
#pragma unroll
        for(int nt=0; nt<NT; nt++) tt[nt] = t0v[nt] + s0*rat[nt];
        eval(tt);

        // ---- k1 extract; stage y + (dt/3)k1 -> buf0
#pragma unroll
        for(int mt=0; mt<MT; mt++){
            const int db = 32*wvd + mt*16 + l4*4;
            f32x4 bv = *(const f32x4*)(b2 + db);
            f32x4 uv = *(const f32x4*)(u2 + db);
#pragma unroll
            for(int nt=0; nt<NT; nt++){
                float v[4];
#pragma unroll
                for(int r2=0;r2<4;r2++){
                    float kk = (acc[mt][nt][r2] + bv[r2] + tt[nt]*uv[r2]) * rat[nt];
                    k1[mt][nt][r2] = kk;
                    v[r2] = fmaf(c3, kk, y[mt][nt][r2]);
                }
                put(0, mt, nt, v[0], v[1], v[2], v[3]);
            }
        }
#pragma unroll
        for(int nt=0; nt<NT; nt++) tt[nt] = t0v[nt] + (s0+c3)*rat[nt];
        eval(tt);

        // ---- k2 extract; stage y + dt*k2 - (dt/3)k1 -> buf0
#pragma unroll
        for(int mt=0; mt<MT; mt++){
            const int db = 32*wvd + mt*16 + l4*4;
            f32x4 bv = *(const f32x4*)(b2 + db);
            f32x4 uv = *(const f32x4*)(u2 + db);
#pragma unroll
            for(int nt=0; nt<NT; nt++){
                float v[4];
#pragma unroll
                for(int r2=0;r2<4;r2++){
                    float kk = (acc[mt][nt][r2] + bv[r2] + tt[nt]*uv[r2]) * rat[nt];
                    k2[mt][nt][r2] = kk;
                    v[r2] = y[mt][nt][r2] + dt*kk - c3*k1[mt][nt][r2];
                }
                put(0, mt, nt, v[0], v[1], v[2], v[3]);
            }
        }
#pragma unroll
        for(int nt=0; nt<NT; nt++) tt[nt] = t0v[nt] + (s0+2.f*c3)*rat[nt];
        eval(tt);

        // ---- k3 extract (folded): stage y + dt*(k1-k2+k3) -> buf0; fold into y
#pragma unroll
        for(int mt=0; mt<MT; mt++){
            const int db = 32*wvd + mt*16 + l4*4;
            f32x4 bv = *(const f32x4*)(b2 + db);
            f32x4 uv = *(const f32x4*)(u2 + db);
#pragma unroll
            for(int nt=0; nt<NT; nt++){
                float v[4];
#pragma unroll
                for(int r2=0;r2<4;r2++){
                    float k3v = (acc[mt][nt][r2] + bv[r2] + tt[nt]*uv[r2]) * rat[nt];
                    float yo = y[mt][nt][r2];
                    v[r2] = yo + dt*(k1[mt][nt][r2] - k2[mt][nt][r2] + k3v);
                    y[mt][nt][r2] = yo + dt8*(k1[mt][nt][r2] + 3.f*(k2[mt][nt][r2] + k3v));
                }
                put(0, mt, nt, v[0], v[1], v[2], v[3]);
            }
        }
#pragma unroll
        for(int nt=0; nt<NT; nt++) tt[nt] = t0v[nt] + s1*rat[nt];
        eval(tt);

        // ---- k4 fold, then transpose through buf1 for coalesced output
        __syncthreads();                 // all matmul2 reads of buf1 done
        {
            float* yf = (float*)&ylds[BUF_USH];  // [32 rows][256 f32], swizzled
#pragma unroll
            for(int mt=0; mt<MT; mt++){
                const int db = 32*wvd + mt*16 + l4*4;
                f32x4 bv = *(const f32x4*)(b2 + db);
                f32x4 uv = *(const f32x4*)(u2 + db);
#pragma unroll
                for(int nt=0; nt<NT; nt++){
                    const int row = nt*16 + l15;
                    f32x4 ov;
#pragma unroll
                    for(int r2=0;r2<4;r2++){
                        float k4v = (acc[mt][nt][r2] + bv[r2] + tt[nt]*uv[r2]) * rat[nt];
                        float yn = fmaf(dt8, k4v, y[mt][nt][r2]);
                        y[mt][nt][r2] = yn;
                        ov[r2] = yn * gw;
                    }
                    const int c = 8*wvd + 4*mt + l4;         // logical 16B granule = d>>2
                    const int p = c ^ (row & 7);
                    *(f32x4*)&yf[row*256 + p*4] = ov;
                }
            }
            __syncthreads();
            // each wave stores 4 rows, 1KB contiguous per row — non-temporal
#pragma unroll
            for(int i=0;i<4;i++){
                const int r = 4*wvd + i;
                f32x4 v = *(const f32x4*)&yf[r*256 + ((lane ^ (r&7))&63)*4];
                __builtin_nontemporal_store(v,
                    (f32x4*)(out + ((size_t)(base + r)*3 + step)*DM + lane*4));
            }
        }
        s0 = s1;
    }
}

extern "C" void kernel_launch(void* const* d_in, const int* in_sizes, int n_in,
                              void* d_out, int out_size, void* d_ws, size_t ws_size,
                              hipStream_t stream)
{
    const float* x  = (const float*)d_in[0];
    const float* t  = (const float*)d_in[1];
    const float* W1 = (const float*)d_in[2];
    const float* b1 = (const float*)d_in[3];
    const float* u1 = (const float*)d_in[4];
    const float* W2 = (const float*)d_in[5];
    const float* b2 = (const float*)d_in[6];
    const float* u2 = (const float*)d_in[7];
    ushort* wpk = (ushort*)d_ws;     // 512 KB: W1hi|W1lo|W2hi|W2lo packed fragments

    pack_w_kernel<<<dim3(256,2), 256, 0, stream>>>(W1, W2, wpk);
    ode_mfma_kernel<<<dim3((4*T_LEN*T_LEN)/NSAMP), 512, 0, stream>>>(
        x, t, b1, u1, b2, u2, wpk, (float*)d_out);
}

// Round 11
// 278.348 us; speedup vs baseline: 3.6871x; 1.4917x over previous
//
#include <hip/hip_runtime.h>
#include <hip/hip_fp16.h>

typedef float f32x4 __attribute__((ext_vector_type(4)));
typedef _Float16 f16x8 __attribute__((ext_vector_type(8)));

#define T_LEN 96
#define DM    256
#define NSAMP 32      // ODE rows per block
#define MT 2          // d-tiles per wave (wave owns 32 d)
#define NT 2          // sample-tiles per wave (wave owns all 32 samples)
#define BUF_USH 8192  // 32 rows * 256 f16 per stage buffer (16KB)
#define LDS_PAD 12288 // pad 32KB -> 56KB: keeps 2-block/CU window -> 128-VGPR budget
                      // (R4-R8: backend sets VGPR target from LDS-permitted occupancy)

// fast softplus: ~8 instr; |err| ~1e-7, threshold 3.9e-2
__device__ __forceinline__ float softplus_f(float x){
    float u = __expf(-fabsf(x));
    return fmaxf(x, 0.f) + __logf(1.0f + u);
}
// pack two f32 -> f16x2 (RNE)
__device__ __forceinline__ uint pkf16(float a, float b){
    uint ha = __half_as_ushort(__float2half_rn(a));
    uint hb = __half_as_ushort(__float2half_rn(b));
    return ha | (hb << 16);
}

// Convert W to f16 and pack into MFMA A-fragment order:
// frag (dt,ks): lane l holds W[dt*16 + (l&15)][ks*32 + (l>>4)*8 + i], i=0..7
// => packed[((dt*8+ks)*64 + l)*8 + i]; wave64 load = contiguous 1KB.
__global__ void pack_w_kernel(const float* __restrict__ W1, const float* __restrict__ W2,
                              ushort* __restrict__ ws){
    int idx = blockIdx.x*256 + threadIdx.x;          // 0..65535
    const float* W = blockIdx.y ? W2 : W1;
    ushort* dst = ws + (size_t)blockIdx.y*65536;     // [W1f16 | W2f16]
    float w = W[idx];
    int d = idx >> 8, k = idx & 255;
    int off = ((((d>>4)<<3) + (k>>5))<<9) + (((d&15) | (((k>>3)&3)<<4))<<3) + (k&7);
    dst[off] = __half_as_ushort(__float2half_rn(w));
}

// R11: f16 single-product MFMA (was bf16 hi/lo 3-product). One f16 product
// rel err 2^-11 ~ the bf16 3-product path for this threshold, but: MFMA /3,
// W L2-traffic /2, LDS stage traffic /2, pack VALU /2.
__global__ __launch_bounds__(512)
void ode_mfma_kernel(const float* __restrict__ x, const float* __restrict__ t,
                     const float* __restrict__ b1, const float* __restrict__ u1,
                     const float* __restrict__ b2, const float* __restrict__ u2,
                     const ushort* __restrict__ wpk, float* __restrict__ out)
{
    // two stage buffers: [buf][row 0..31][256 f16]; 16B granules XOR-swizzled
    // by (row&7) (row stride 512B -> granule bits 0..2 are the only bank bits)
    __shared__ __align__(16) ushort ylds[2*BUF_USH + LDS_PAD];

    const int tid  = threadIdx.x;
    const int wvd  = tid >> 6;       // wave 0..7 owns d in [32*wvd, 32*wvd+32)
    const int lane = tid & 63;
    const int l15  = lane & 15;
    const int l4   = lane >> 4;
    const int base = blockIdx.x * NSAMP;

    float t0v[NT], rat[NT];
    float y[MT][NT][4], k1[MT][NT][4], k2[MT][NT][4];
    f32x4 acc[MT][NT];

#pragma unroll
    for(int nt=0; nt<NT; nt++){
        int n = base + nt*16 + l15;
        int b = n / (T_LEN*T_LEN);
        int r = n - b*(T_LEN*T_LEN);
        int q = r / T_LEN;
        int j = r - q*T_LEN;
        float ta = t[b*T_LEN + j], tb = t[b*T_LEN + q];
        t0v[nt] = ta; rat[nt] = tb - ta;
        const float* xr = x + (size_t)(b*T_LEN + j)*DM;
#pragma unroll
        for(int mt=0; mt<MT; mt++){
            const int db = 32*wvd + mt*16 + l4*4;
            f32x4 v = *(const f32x4*)(xr + db);
#pragma unroll
            for(int r2=0;r2<4;r2++) y[mt][nt][r2] = v[r2];
        }
    }

    // write 4 consecutive-d values as f16 (8B) into stage buffer `buf`
    auto put = [&](int buf, int mt, int nt, float v0, float v1, float v2, float v3){
        uint p0 = pkf16(v0, v1), p1 = pkf16(v2, v3);
        int row = nt*16 + l15;
        int g   = 4*wvd + 2*mt + (l4>>1);       // logical 16B granule (0..31)
        int gs  = g ^ (row & 7);                // swizzle low 3 granule bits
        int idx = buf*BUF_USH + row*256 + gs*8 + (l4&1)*4;
        *(uint2*)&ylds[idx] = make_uint2(p0, p1);
    };

    // acc[mt][nt] = (W-slice) x Y^T over K=256, single f16 product
    auto matmul = [&](const ushort* Wf, int buf){
        const int bbase = buf*BUF_USH;
#pragma unroll
        for(int mt=0; mt<MT; mt++)
#pragma unroll
            for(int nt=0; nt<NT; nt++)
                acc[mt][nt] = (f32x4){0.f,0.f,0.f,0.f};
#pragma unroll 2
        for(int ks=0; ks<8; ks++){
            f16x8 ah[MT];
#pragma unroll
            for(int mt=0; mt<MT; mt++){
                const int off = ((((2*wvd+mt)<<3)+ks)<<9) + (lane<<3);
                ah[mt] = *(const f16x8*)(Wf + off);
            }
#pragma unroll
            for(int nt=0; nt<NT; nt++){
                const int row = nt*16 + l15;
                const int gx  = (ks*4 + l4) ^ (row & 7);
                f16x8 bh = *(const f16x8*)&ylds[bbase + row*256 + gx*8];
#pragma unroll
                for(int mt=0; mt<MT; mt++)
                    acc[mt][nt] = __builtin_amdgcn_mfma_f32_16x16x32_f16(ah[mt], bh, acc[mt][nt], 0,0,0);
            }
        }
    };

    // input staged in buf0 by caller; leaves layer-2 raw acc for caller
    auto eval = [&](const float* ttv){
        __syncthreads();                 // all puts to buf0 done
        matmul(wpk, 0);                  // layer 1 reads buf0
#pragma unroll
        for(int mt=0; mt<MT; mt++){
            const int db = 32*wvd + mt*16 + l4*4;
            f32x4 bv = *(const f32x4*)(b1 + db);
            f32x4 uv = *(const f32x4*)(u1 + db);
#pragma unroll
            for(int nt=0; nt<NT; nt++){
                float v[4];
#pragma unroll
                for(int r2=0;r2<4;r2++)
                    v[r2] = softplus_f(acc[mt][nt][r2] + bv[r2] + ttv[nt]*uv[r2]);
                put(1, mt, nt, v[0], v[1], v[2], v[3]);
            }
        }
        __syncthreads();                 // all puts to buf1 done
        matmul(wpk + 65536, 1);          // layer 2 reads buf1
    };

    float s0 = 0.f;
#pragma unroll 1
    for(int step=0; step<3; step++){
        const float s1 = (step==0) ? 0.1127016653792583f : ((step==1) ? 0.5f : 0.8872983346207417f);
        const float gw = ((step==1) ? 0.88888f : 0.55555f) * 0.5f;
        const float dt = s1 - s0;
        const float c3 = dt * (1.f/3.f);
        const float dt8 = dt * 0.125f;
        float tt[NT];

        // ---- eval 1: f(s0, y) -> k1   (stage y into buf0)
#pragma unroll
        for(int mt=0; mt<MT; mt++)
#pragma unroll
            for(int nt=0; nt<NT; nt++)
                put(0, mt, nt, y[mt][nt][0], y[mt][nt][1], y[mt][nt][2], y[mt][nt][3]);
#pragma unroll
        for(int nt=0; nt<NT; nt++) tt[nt] = t0v[nt] + s0*rat[nt];
        eval(tt);

        // ---- k1 extract; stage y + (dt/3)k1 -> buf0
#pragma unroll
        for(int mt=0; mt<MT; mt++){
            const int db = 32*wvd + mt*16 + l4*4;
            f32x4 bv = *(const f32x4*)(b2 + db);
            f32x4 uv = *(const f32x4*)(u2 + db);
#pragma unroll
            for(int nt=0; nt<NT; nt++){
                float v[4];
#pragma unroll
                for(int r2=0;r2<4;r2++){
                    float kk = (acc[mt][nt][r2] + bv[r2] + tt[nt]*uv[r2]) * rat[nt];
                    k1[mt][nt][r2] = kk;
                    v[r2] = fmaf(c3, kk, y[mt][nt][r2]);
                }
                put(0, mt, nt, v[0], v[1], v[2], v[3]);
            }
        }
#pragma unroll
        for(int nt=0; nt<NT; nt++) tt[nt] = t0v[nt] + (s0+c3)*rat[nt];
        eval(tt);

        // ---- k2 extract; stage y + dt*k2 - (dt/3)k1 -> buf0
#pragma unroll
        for(int mt=0; mt<MT; mt++){
            const int db = 32*wvd + mt*16 + l4*4;
            f32x4 bv = *(const f32x4*)(b2 + db);
            f32x4 uv = *(const f32x4*)(u2 + db);
#pragma unroll
            for(int nt=0; nt<NT; nt++){
                float v[4];
#pragma unroll
                for(int r2=0;r2<4;r2++){
                    float kk = (acc[mt][nt][r2] + bv[r2] + tt[nt]*uv[r2]) * rat[nt];
                    k2[mt][nt][r2] = kk;
                    v[r2] = y[mt][nt][r2] + dt*kk - c3*k1[mt][nt][r2];
                }
                put(0, mt, nt, v[0], v[1], v[2], v[3]);
            }
        }
#pragma unroll
        for(int nt=0; nt<NT; nt++) tt[nt] = t0v[nt] + (s0+2.f*c3)*rat[nt];
        eval(tt);

        // ---- k3 extract (folded): stage y + dt*(k1-k2+k3) -> buf0; fold into y
#pragma unroll
        for(int mt=0; mt<MT; mt++){
            const int db = 32*wvd + mt*16 + l4*4;
            f32x4 bv = *(const f32x4*)(b2 + db);
            f32x4 uv = *(const f32x4*)(u2 + db);
#pragma unroll
            for(int nt=0; nt<NT; nt++){
                float v[4];
#pragma unroll
                for(int r2=0;r2<4;r2++){
                    float k3v = (acc[mt][nt][r2] + bv[r2] + tt[nt]*uv[r2]) * rat[nt];
                    float yo = y[mt][nt][r2];
                    v[r2] = yo + dt*(k1[mt][nt][r2] - k2[mt][nt][r2] + k3v);
                    y[mt][nt][r2] = yo + dt8*(k1[mt][nt][r2] + 3.f*(k2[mt][nt][r2] + k3v));
                }
                put(0, mt, nt, v[0], v[1], v[2], v[3]);
            }
        }
#pragma unroll
        for(int nt=0; nt<NT; nt++) tt[nt] = t0v[nt] + s1*rat[nt];
        eval(tt);

        // ---- k4 fold, then transpose for coalesced output.
        // yf lives at byte 24576..57344 (pad + dead buf1) so it does NOT
        // overlap buf0 — next step's buf0 puts can't race pending yf reads.
        __syncthreads();                 // all matmul2 reads of buf1 done
        {
            float* yf = (float*)&ylds[LDS_PAD];  // [32 rows][256 f32], swizzled
#pragma unroll
            for(int mt=0; mt<MT; mt++){
                const int db = 32*wvd + mt*16 + l4*4;
                f32x4 bv = *(const f32x4*)(b2 + db);
                f32x4 uv = *(const f32x4*)(u2 + db);
#pragma unroll
                for(int nt=0; nt<NT; nt++){
                    const int row = nt*16 + l15;
                    f32x4 ov;
#pragma unroll
                    for(int r2=0;r2<4;r2++){
                        float k4v = (acc[mt][nt][r2] + bv[r2] + tt[nt]*uv[r2]) * rat[nt];
                        float yn = fmaf(dt8, k4v, y[mt][nt][r2]);
                        y[mt][nt][r2] = yn;
                        ov[r2] = yn * gw;
                    }
                    const int c = 8*wvd + 4*mt + l4;         // logical 16B granule = d>>2
                    const int p = c ^ (row & 7);
                    *(f32x4*)&yf[row*256 + p*4] = ov;
                }
            }
            __syncthreads();
            // each wave stores 4 rows, 1KB contiguous per row — non-temporal
#pragma unroll
            for(int i=0;i<4;i++){
                const int r = 4*wvd + i;
                f32x4 v = *(const f32x4*)&yf[r*256 + ((lane ^ (r&7))&63)*4];
                __builtin_nontemporal_store(v,
                    (f32x4*)(out + ((size_t)(base + r)*3 + step)*DM + lane*4));
            }
        }
        s0 = s1;
    }
}

extern "C" void kernel_launch(void* const* d_in, const int* in_sizes, int n_in,
                              void* d_out, int out_size, void* d_ws, size_t ws_size,
                              hipStream_t stream)
{
    const float* x  = (const float*)d_in[0];
    const float* t  = (const float*)d_in[1];
    const float* W1 = (const float*)d_in[2];
    const float* b1 = (const float*)d_in[3];
    const float* u1 = (const float*)d_in[4];
    const float* W2 = (const float*)d_in[5];
    const float* b2 = (const float*)d_in[6];
    const float* u2 = (const float*)d_in[7];
    ushort* wpk = (ushort*)d_ws;     // 256 KB: W1f16 | W2f16 packed fragments

    pack_w_kernel<<<dim3(256,2), 256, 0, stream>>>(W1, W2, wpk);
    ode_mfma_kernel<<<dim3((4*T_LEN*T_LEN)/NSAMP), 512, 0, stream>>>(
        x, t, b1, u1, b2, u2, wpk, (float*)d_out);
}

// Round 13
// 260.511 us; speedup vs baseline: 3.9396x; 1.0685x over previous
//
#include <hip/hip_runtime.h>
#include <hip/hip_fp16.h>

typedef float f32x4 __attribute__((ext_vector_type(4)));
typedef _Float16 f16x8 __attribute__((ext_vector_type(8)));
typedef __fp16 fp16x2 __attribute__((ext_vector_type(2)));   // cvt_pkrtz return type

#define T_LEN 96
#define DM    256
#define NSAMP 32      // ODE rows per block
#define MT 2          // d-tiles per wave (wave owns 32 d)
#define NT 2          // sample-tiles per wave
#define BUF_USH 8192  // 32 rows * 256 f16 per stage buffer (16KB)
// LDS map (bytes): buf0 [0,16K), buf1 [16K,32K), yf [32K,64K) — all disjoint.
// Total 64KB: 2 blocks/CU fit (<=80KB), 3 don't -> backend's LDS-derived
// occupancy target stays 4 waves/EU -> 128-VGPR budget (R4-R9 lesson).

// fast softplus: ~8 instr; |err| ~1e-7, threshold 3.9e-2
__device__ __forceinline__ float softplus_f(float x){
    float u = __expf(-fabsf(x));
    return fmaxf(x, 0.f) + __logf(1.0f + u);
}
// two f32 -> packed f16x2, single instruction (RTZ; rel err 2^-10 worst-case,
// fine against 3.9e-2 threshold)
__device__ __forceinline__ uint pkrtz(float a, float b){
    fp16x2 h = __builtin_amdgcn_cvt_pkrtz(a, b);
    return *(uint*)&h;
}

// Convert W to f16 and pack into MFMA A-fragment order:
// frag (dt,ks): lane l holds W[dt*16 + (l&15)][ks*32 + (l>>4)*8 + i], i=0..7
// => packed[((dt*8+ks)*64 + l)*8 + i]; wave64 load = contiguous 1KB.
__global__ void pack_w_kernel(const float* __restrict__ W1, const float* __restrict__ W2,
                              ushort* __restrict__ ws){
    int idx = blockIdx.x*256 + threadIdx.x;          // 0..65535
    const float* W = blockIdx.y ? W2 : W1;
    ushort* dst = ws + (size_t)blockIdx.y*65536;     // [W1f16 | W2f16]
    float w = W[idx];
    int d = idx >> 8, k = idx & 255;
    int off = ((((d>>4)<<3) + (k>>5))<<9) + (((d&15) | (((k>>3)&3)<<4))<<3) + (k&7);
    dst[off] = __half_as_ushort(__float2half_rn(w));
}

__global__ __launch_bounds__(512)
void ode_mfma_kernel(const float* __restrict__ x, const float* __restrict__ t,
                     const float* __restrict__ b1, const float* __restrict__ u1,
                     const float* __restrict__ b2, const float* __restrict__ u2,
                     const ushort* __restrict__ wpk, float* __restrict__ out)
{
    __shared__ __align__(16) ushort ylds[4*BUF_USH];   // 64KB, map above

    const int tid  = threadIdx.x;
    const int wvd  = tid >> 6;       // wave 0..7 owns d in [32*wvd, 32*wvd+32)
    const int lane = tid & 63;
    const int l15  = lane & 15;
    const int l4   = lane >> 4;
    const int base = blockIdx.x * NSAMP;

    float t0v[NT], rat[NT];
    float y[MT][NT][4], k1[MT][NT][4], k2[MT][NT][4];
    f32x4 acc[MT][NT];

    // B-read swizzled base byte-offsets, hoisted: read addr = vb[nt] ^ (64*ks)
    // (derivation: 16*((4ks+l4)^(row&7)) = 64*(ks^r2) + 16*(l4^(row&3)),
    //  r2=(row>>2)&1; 64*(ks^r2) = (64ks)^(64r2); no carries into other bits)
    int vb[NT];
#pragma unroll
    for(int nt=0; nt<NT; nt++){
        int row = nt*16 + l15;
        vb[nt] = row*512 + ((l4 ^ (row&3))*16) + ((row&4)*16);
    }

#pragma unroll
    for(int nt=0; nt<NT; nt++){
        int n = base + nt*16 + l15;
        int b = n / (T_LEN*T_LEN);
        int r = n - b*(T_LEN*T_LEN);
        int q = r / T_LEN;
        int j = r - q*T_LEN;
        float ta = t[b*T_LEN + j], tb = t[b*T_LEN + q];
        t0v[nt] = ta; rat[nt] = tb - ta;
        const float* xr = x + (size_t)(b*T_LEN + j)*DM;
#pragma unroll
        for(int mt=0; mt<MT; mt++){
            const int db = 32*wvd + mt*16 + l4*4;
            f32x4 v = *(const f32x4*)(xr + db);
#pragma unroll
            for(int r2=0;r2<4;r2++) y[mt][nt][r2] = v[r2];
        }
    }

    // write 4 consecutive-d values as f16 (8B) into stage buffer `buf`
    auto put = [&](int buf, int mt, int nt, float v0, float v1, float v2, float v3){
        uint p0 = pkrtz(v0, v1), p1 = pkrtz(v2, v3);
        int row = nt*16 + l15;
        int g   = 4*wvd + 2*mt + (l4>>1);       // logical 16B granule (0..31)
        int gs  = g ^ (row & 7);                // swizzle low 3 granule bits
        int idx = buf*BUF_USH + row*256 + gs*8 + (l4&1)*4;
        *(uint2*)&ylds[idx] = make_uint2(p0, p1);
    };

    // acc[mt][nt] = (W-slice) x Y^T over K=256, single f16 product
    auto matmul = [&](const ushort* Wf, int buf){
        const char* bb = (const char*)ylds + (buf<<14);
        __builtin_amdgcn_s_setprio(1);
#pragma unroll
        for(int mt=0; mt<MT; mt++)
#pragma unroll
            for(int nt=0; nt<NT; nt++)
                acc[mt][nt] = (f32x4){0.f,0.f,0.f,0.f};
#pragma unroll 2
        for(int ks=0; ks<8; ks++){
            f16x8 ah[MT];
#pragma unroll
            for(int mt=0; mt<MT; mt++){
                const int off = ((((2*wvd+mt)<<3)+ks)<<9) + (lane<<3);
                ah[mt] = *(const f16x8*)(Wf + off);
            }
#pragma unroll
            for(int nt=0; nt<NT; nt++){
                f16x8 bh = *(const f16x8*)(bb + (vb[nt] ^ (ks<<6)));
#pragma unroll
                for(int mt=0; mt<MT; mt++)
                    acc[mt][nt] = __builtin_amdgcn_mfma_f32_16x16x32_f16(ah[mt], bh, acc[mt][nt], 0,0,0);
            }
        }
        __builtin_amdgcn_s_setprio(0);
    };

    // softplus + stage hidden into buf1 (after matmul1's acc)
    auto hidden = [&](const float* ttv){
#pragma unroll
        for(int mt=0; mt<MT; mt++){
            const int db = 32*wvd + mt*16 + l4*4;
            f32x4 bv = *(const f32x4*)(b1 + db);
            f32x4 uv = *(const f32x4*)(u1 + db);
#pragma unroll
            for(int nt=0; nt<NT; nt++){
                float v[4];
#pragma unroll
                for(int r2=0;r2<4;r2++)
                    v[r2] = softplus_f(acc[mt][nt][r2] + bv[r2] + ttv[nt]*uv[r2]);
                put(1, mt, nt, v[0], v[1], v[2], v[3]);
            }
        }
    };

    // ---- initial stage of y into buf0
#pragma unroll
    for(int mt=0; mt<MT; mt++)
#pragma unroll
        for(int nt=0; nt<NT; nt++)
            put(0, mt, nt, y[mt][nt][0], y[mt][nt][1], y[mt][nt][2], y[mt][nt][3]);
    __syncthreads();

    float s0 = 0.f;
#pragma unroll 1
    for(int step=0; step<3; step++){
        const float s1 = (step==0) ? 0.1127016653792583f : ((step==1) ? 0.5f : 0.8872983346207417f);
        const float gw = ((step==1) ? 0.88888f : 0.55555f) * 0.5f;
        const float dt = s1 - s0;
        const float c3 = dt * (1.f/3.f);
        const float dt8 = dt * 0.125f;
        float tt[NT];

        // ---- E1 (no leading barrier: buf0 staged before the barrier that
        //      ended the previous iteration / the init barrier; the output
        //      stores issued after that barrier overlap this matmul1)
#pragma unroll
        for(int nt=0; nt<NT; nt++) tt[nt] = t0v[nt] + s0*rat[nt];
        matmul(wpk, 0);
        hidden(tt);
        __syncthreads();
        matmul(wpk + 65536, 1);

        // ---- k1 extract; stage y + (dt/3)k1 -> buf0 (buf0 free: all waves
        //      passed the post-hidden barrier after their matmul1)
#pragma unroll
        for(int mt=0; mt<MT; mt++){
            const int db = 32*wvd + mt*16 + l4*4;
            f32x4 bv = *(const f32x4*)(b2 + db);
            f32x4 uv = *(const f32x4*)(u2 + db);
#pragma unroll
            for(int nt=0; nt<NT; nt++){
                float v[4];
#pragma unroll
                for(int r2=0;r2<4;r2++){
                    float kk = (acc[mt][nt][r2] + bv[r2] + tt[nt]*uv[r2]) * rat[nt];
                    k1[mt][nt][r2] = kk;
                    v[r2] = fmaf(c3, kk, y[mt][nt][r2]);
                }
                put(0, mt, nt, v[0], v[1], v[2], v[3]);
            }
        }
        __syncthreads();

        // ---- E2
#pragma unroll
        for(int nt=0; nt<NT; nt++) tt[nt] = t0v[nt] + (s0+c3)*rat[nt];
        matmul(wpk, 0);
        hidden(tt);
        __syncthreads();
        matmul(wpk + 65536, 1);

        // ---- k2 extract; stage y + dt*k2 - (dt/3)k1 -> buf0
#pragma unroll
        for(int mt=0; mt<MT; mt++){
            const int db = 32*wvd + mt*16 + l4*4;
            f32x4 bv = *(const f32x4*)(b2 + db);
            f32x4 uv = *(const f32x4*)(u2 + db);
#pragma unroll
            for(int nt=0; nt<NT; nt++){
                float v[4];
#pragma unroll
                for(int r2=0;r2<4;r2++){
                    float kk = (acc[mt][nt][r2] + bv[r2] + tt[nt]*uv[r2]) * rat[nt];
                    k2[mt][nt][r2] = kk;
                    v[r2] = y[mt][nt][r2] + dt*kk - c3*k1[mt][nt][r2];
                }
                put(0, mt, nt, v[0], v[1], v[2], v[3]);
            }
        }
        __syncthreads();

        // ---- E3
#pragma unroll
        for(int nt=0; nt<NT; nt++) tt[nt] = t0v[nt] + (s0+2.f*c3)*rat[nt];
        matmul(wpk, 0);
        hidden(tt);
        __syncthreads();
        matmul(wpk + 65536, 1);

        // ---- k3 extract (folded): stage y + dt*(k1-k2+k3) -> buf0; fold y
#pragma unroll
        for(int mt=0; mt<MT; mt++){
            const int db = 32*wvd + mt*16 + l4*4;
            f32x4 bv = *(const f32x4*)(b2 + db);
            f32x4 uv = *(const f32x4*)(u2 + db);
#pragma unroll
            for(int nt=0; nt<NT; nt++){
                float v[4];
#pragma unroll
                for(int r2=0;r2<4;r2++){
                    float k3v = (acc[mt][nt][r2] + bv[r2] + tt[nt]*uv[r2]) * rat[nt];
                    float yo = y[mt][nt][r2];
                    v[r2] = yo + dt*(k1[mt][nt][r2] - k2[mt][nt][r2] + k3v);
                    y[mt][nt][r2] = yo + dt8*(k1[mt][nt][r2] + 3.f*(k2[mt][nt][r2] + k3v));
                }
                put(0, mt, nt, v[0], v[1], v[2], v[3]);
            }
        }
        __syncthreads();

        // ---- E4
#pragma unroll
        for(int nt=0; nt<NT; nt++) tt[nt] = t0v[nt] + s1*rat[nt];
        matmul(wpk, 0);
        hidden(tt);
        __syncthreads();
        matmul(wpk + 65536, 1);

        // ---- k4 extract + fold + stage next y (buf0) + transpose scratch (yf).
        //      No barrier needed first: buf0's last reader was this step's E4
        //      matmul1 (fenced by E4's internal barrier); yf is disjoint from
        //      buf0/buf1 and its last readers finished before this step began.
        {
            float* yf = (float*)&ylds[2*BUF_USH];   // [32 rows][256 f32], swizzled
#pragma unroll
            for(int mt=0; mt<MT; mt++){
                const int db = 32*wvd + mt*16 + l4*4;
                f32x4 bv = *(const f32x4*)(b2 + db);
                f32x4 uv = *(const f32x4*)(u2 + db);
#pragma unroll
                for(int nt=0; nt<NT; nt++){
                    const int row = nt*16 + l15;
                    f32x4 ov;
#pragma unroll
                    for(int r2=0;r2<4;r2++){
                        float k4v = (acc[mt][nt][r2] + bv[r2] + tt[nt]*uv[r2]) * rat[nt];
                        float yn = fmaf(dt8, k4v, y[mt][nt][r2]);
                        y[mt][nt][r2] = yn;
                        ov[r2] = yn * gw;
                    }
                    put(0, mt, nt, y[mt][nt][0], y[mt][nt][1], y[mt][nt][2], y[mt][nt][3]);
                    const int c = 8*wvd + 4*mt + l4;         // logical 16B granule = d>>2
                    const int p = c ^ (row & 7);
                    *(f32x4*)&yf[row*256 + p*4] = ov;
                }
            }
            __syncthreads();
            // stores issued here overlap the next iteration's matmul1
#pragma unroll
            for(int i=0;i<4;i++){
                const int r = 4*wvd + i;
                f32x4 v = *(const f32x4*)&yf[r*256 + ((lane ^ (r&7))&63)*4];
                __builtin_nontemporal_store(v,
                    (f32x4*)(out + ((size_t)(base + r)*3 + step)*DM + lane*4));
            }
        }
        s0 = s1;
    }
}

extern "C" void kernel_launch(void* const* d_in, const int* in_sizes, int n_in,
                              void* d_out, int out_size, void* d_ws, size_t ws_size,
                              hipStream_t stream)
{
    const float* x  = (const float*)d_in[0];
    const float* t  = (const float*)d_in[1];
    const float* W1 = (const float*)d_in[2];
    const float* b1 = (const float*)d_in[3];
    const float* u1 = (const float*)d_in[4];
    const float* W2 = (const float*)d_in[5];
    const float* b2 = (const float*)d_in[6];
    const float* u2 = (const float*)d_in[7];
    ushort* wpk = (ushort*)d_ws;     // 256 KB: W1f16 | W2f16 packed fragments

    pack_w_kernel<<<dim3(256,2), 256, 0, stream>>>(W1, W2, wpk);
    ode_mfma_kernel<<<dim3((4*T_LEN*T_LEN)/NSAMP), 512, 0, stream>>>(
        x, t, b1, u1, b2, u2, wpk, (float*)d_out);
}